// Round 6
// baseline (264.322 us; speedup 1.0000x reference)
//
#include <hip/hip_runtime.h>

// DART_Net fused kernel, MI355X (gfx950). Round 6.
// B=64, N=128, M=64, LH=LO=128. Output [B*N] fp32.
//
// R6 vs R5 (R5: 185 us, VALUBusy 60%, occ 27% = 2.2 blocks/CU, latency-bound):
//  - 512-thread blocks (8 waves = 4 rowgrps x 2 atomgrps). Same ~39 KB LDS now
//    feeds 8 waves instead of 4 -> 16 waves/CU at 2 resident blocks (the LDS
//    pool, not 160KB nominal, was capping us at ~2 blocks).
//  - W1 stored SoA in LDS (x/y/z/b arrays); layer-1 fma chains use
//    v_pk_fma_f32 on channel pairs (w-pairs are natural ds_read_b64), halving
//    layer-1 FMA issue count.
//  - i-species: one ob per wave (8 waves = 8 obs), no atomics.

typedef __attribute__((ext_vector_type(8))) short short8;   // bf16x8 frag
typedef __attribute__((ext_vector_type(4))) float f32x4;
typedef __attribute__((ext_vector_type(2))) float f32x2;
typedef __attribute__((ext_vector_type(4))) unsigned uint4v;

#define G_ 8
#define NATOMS (64 * 128)

// LDS layout (bytes):
//   [    0, 32768)  sBf  : bf16 B-frags [ob*4+kb][lane] (16B each)
//                   (after species: sH1 @0 [8*64], sH2 @2048 [8*32], sH3 @3072)
//   [32768, 33280)  sW1x[128]   [33280, 33792) sW1y[128]
//   [33792, 34304)  sW1z[128]   [34304, 34816) sW1b[128]
//   [34816, 35328)  sB2[128]
//   [35328, 39424)  sAtm[8][128]
//   [39424, 39456)  sIm[8]
#define LDS_BYTES 39456

struct DartParams {
  const float* x[4];    // aj, ak, al, ai
  const float* W1[4];
  const float* b1[4];
  const float* W2[4];
  const float* b2[4];
  const float* HW[4];   // 64x128, 32x64, 16x32, 1x16
  const float* Hb[4];
  float* out;
};

__device__ __forceinline__ float celu01(float z) {
  // celu(z, alpha=0.1) = max(z,0) + min(0.1*(exp(10z)-1), 0)
  float e = __builtin_amdgcn_exp2f(z * 14.42695040888963f);
  return fmaxf(z, 0.0f) + fminf(fmaf(0.1f, e, -0.1f), 0.0f);
}

__device__ __forceinline__ unsigned cvtpk(float a, float b) {
  unsigned r;
  asm("v_cvt_pk_bf16_f32 %0, %1, %2" : "=v"(r) : "v"(a), "v"(b));
  return r;
}
__device__ __forceinline__ short8 pack4(unsigned a, unsigned b, unsigned c, unsigned d) {
  uint4v u = {a, b, c, d};
  return __builtin_bit_cast(short8, u);
}
__device__ __forceinline__ f32x2 pkfma(f32x2 a, f32x2 b, f32x2 c) {
  f32x2 d;
  asm("v_pk_fma_f32 %0, %1, %2, %3" : "=v"(d) : "v"(a), "v"(b), "v"(c));
  return d;
}

// Stage one species' weights into LDS. Leading barrier protects prior
// readers, trailing barrier publishes. 512 threads.
__device__ __forceinline__ void stage_species(
    const float* W1g, const float* b1g, const float* W2g, const float* b2g,
    float* sW1x, float* sW1y, float* sW1z, float* sW1b,
    float* sB2v, short8* sBfv,
    int t, int lane, int lq, int lr, int wave) {
  __syncthreads();
  if (t < 128) {
    const float* w = W1g + t * 3;
    sW1x[t] = w[0]; sW1y[t] = w[1]; sW1z[t] = w[2];
    sW1b[t] = b1g[t];
    sB2v[t] = b2g[t];
  }
#pragma unroll
  for (int ff = 0; ff < 4; ++ff) {
    const int f  = wave * 4 + ff;            // 8 waves x 4 = 32 frags
    const int ob = f >> 2, kb = f & 3;
    const f32x4* src = (const f32x4*)(W2g + (ob * 16 + lr) * 128 + kb * 32 + lq * 8);
    f32x4 lo = src[0], hi = src[1];
    sBfv[f * 64 + lane] = pack4(cvtpk(lo.x, lo.y), cvtpk(lo.z, lo.w),
                                cvtpk(hi.x, hi.y), cvtpk(hi.z, hi.w));
  }
  __syncthreads();
}

extern "C" __global__ __launch_bounds__(512, 2)
void dart_fused(DartParams p) {
  __shared__ __align__(16) char lds[LDS_BYTES];
  short8* sBfv = (short8*)lds;
  float*  sW1x = (float*)(lds + 32768);
  float*  sW1y = (float*)(lds + 33280);
  float*  sW1z = (float*)(lds + 33792);
  float*  sW1b = (float*)(lds + 34304);
  float*  sB2v = (float*)(lds + 34816);
  float*  sAtm = (float*)(lds + 35328);   // [8*128]
  float*  sIm  = (float*)(lds + 39424);   // [8]
  float*  sH1  = (float*)lds;             // [8*64]  (after species)
  float*  sH2  = (float*)(lds + 2048);    // [8*32]
  float*  sH3  = (float*)(lds + 3072);    // [8*16]

  const int t    = threadIdx.x;
  const int lane = t & 63;
  const int wave = t >> 6;        // 0..7
  const int rowg = wave & 3;      // row group: rows rowg*16 .. +15
  const int atg  = wave >> 2;     // atom group: atoms atg*4 .. +3
  const int lq   = lane >> 4;
  const int lr   = lane & 15;
  const int atom0 = (int)blockIdx.x * G_;

  for (int i = t; i < G_ * 128; i += 512) sAtm[i] = 0.0f;

  // ---------------- species j, k, l ----------------
#pragma unroll 1
  for (int s = 0; s < 3; ++s) {
    stage_species(p.W1[s], p.b1[s], p.W2[s], p.b2[s],
                  sW1x, sW1y, sW1z, sW1b, sB2v, sBfv, t, lane, lq, lr, wave);

    float b2r[8];
#pragma unroll
    for (int ob = 0; ob < 8; ++ob) b2r[ob] = sB2v[ob * 16 + lr];

    const float* X = p.x[s];
    const int rowoff = rowg * 16 + lr;
    const int abase  = atom0 + atg * 4;   // this wave's 4 atoms

    // prefetch pair 0 (atoms abase+0, abase+1)
    float pxa[3], pxb[3];
    {
      const float* xa = X + ((abase + 0) * 64 + rowoff) * 3;
      const float* xb = X + ((abase + 1) * 64 + rowoff) * 3;
      pxa[0] = xa[0]; pxa[1] = xa[1]; pxa[2] = xa[2];
      pxb[0] = xb[0]; pxb[1] = xb[1]; pxb[2] = xb[2];
    }

#pragma unroll 1
    for (int pp = 0; pp < 2; ++pp) {
      const int g0 = atg * 4 + 2 * pp, g1 = g0 + 1;   // block-local atoms
      const float xa0 = pxa[0], xa1 = pxa[1], xa2 = pxa[2];
      const float xb0 = pxb[0], xb1 = pxb[1], xb2 = pxb[2];
      if (pp == 0) {
        const float* xa = X + ((abase + 2) * 64 + rowoff) * 3;
        const float* xb = X + ((abase + 3) * 64 + rowoff) * 3;
        pxa[0] = xa[0]; pxa[1] = xa[1]; pxa[2] = xa[2];
        pxb[0] = xb[0]; pxb[1] = xb[1]; pxb[2] = xb[2];
      }
      const unsigned mwa = (unsigned)__ballot((xa0 + xa1 + xa2) != 0.0f);
      const unsigned mwb = (unsigned)__ballot((xb0 + xb1 + xb2) != 0.0f);
      float mra[4], mrb[4];
#pragma unroll
      for (int j = 0; j < 4; ++j) {
        mra[j] = (float)((mwa >> (lq * 4 + j)) & 1u);
        mrb[j] = (float)((mwb >> (lq * 4 + j)) & 1u);
      }

      // ---- layer 1: pk_fma chains over channel pairs + celu + cvt_pk ----
      const f32x2 xsa0 = {xa0, xa0}, xsa1 = {xa1, xa1}, xsa2 = {xa2, xa2};
      const f32x2 xsb0 = {xb0, xb0}, xsb1 = {xb1, xb1}, xsb2 = {xb2, xb2};
      short8 afa[4], afb[4];
#pragma unroll
      for (int kb = 0; kb < 4; ++kb) {
        const int c0 = kb * 32 + lq * 8;
        unsigned ua[4], ub[4];
#pragma unroll
        for (int e2 = 0; e2 < 4; ++e2) {
          const int c = c0 + e2 * 2;
          f32x2 wx = *(const f32x2*)(sW1x + c);
          f32x2 wy = *(const f32x2*)(sW1y + c);
          f32x2 wz = *(const f32x2*)(sW1z + c);
          f32x2 wb = *(const f32x2*)(sW1b + c);
          f32x2 za = pkfma(xsa0, wx, pkfma(xsa1, wy, pkfma(xsa2, wz, wb)));
          f32x2 zb = pkfma(xsb0, wx, pkfma(xsb1, wy, pkfma(xsb2, wz, wb)));
          ua[e2] = cvtpk(celu01(za.x), celu01(za.y));
          ub[e2] = cvtpk(celu01(zb.x), celu01(zb.y));
        }
        afa[kb] = pack4(ua[0], ua[1], ua[2], ua[3]);
        afb[kb] = pack4(ub[0], ub[1], ub[2], ub[3]);
      }

      // ---- per-ob: shared B-frag reads, 8 MFMAs (2 atoms), epilogue ----
#pragma unroll
      for (int ob = 0; ob < 8; ++ob) {
        const short8* fb = sBfv + (ob * 4) * 64 + lane;
        const float bv = b2r[ob];
        f32x4 a0 = {bv, bv, bv, bv};
        f32x4 a1 = a0;
#pragma unroll
        for (int kb = 0; kb < 4; ++kb) {
          short8 fr = fb[kb * 64];
          a0 = __builtin_amdgcn_mfma_f32_16x16x32_bf16(afa[kb], fr, a0, 0, 0, 0);
          a1 = __builtin_amdgcn_mfma_f32_16x16x32_bf16(afb[kb], fr, a1, 0, 0, 0);
        }
        float p0 = 0.0f, p1 = 0.0f;
#pragma unroll
        for (int j = 0; j < 4; ++j) {
          p0 = fmaf(celu01(a0[j]), mra[j], p0);
          p1 = fmaf(celu01(a1[j]), mrb[j], p1);
        }
        p0 += __shfl_xor(p0, 16, 64);
        p0 += __shfl_xor(p0, 32, 64);
        p1 += __shfl_xor(p1, 16, 64);
        p1 += __shfl_xor(p1, 32, 64);
        const int col = ob * 16 + lr;
        if (lane < 16) {
          atomicAdd(&sAtm[g0 * 128 + col], p0);
          atomicAdd(&sAtm[g1 * 128 + col], p1);
        }
      }
    }
  }

  // ---------------- species i: one 16-row GEMM (rows = atoms) ----------------
  {
    stage_species(p.W1[3], p.b1[3], p.W2[3], p.b2[3],
                  sW1x, sW1y, sW1z, sW1b, sB2v, sBfv, t, lane, lq, lr, wave);
    // (leading barrier also guarantees all j/k/l sAtm atomics complete)

    const int ri = min(atom0 + lr, NATOMS - 1);
    const float* xp = p.x[3] + ri * 3;
    const float x0 = xp[0], x1 = xp[1], x2 = xp[2];
    const unsigned mbi = (unsigned)__ballot((x0 + x1 + x2) != 0.0f);

    const f32x2 xs0 = {x0, x0}, xs1 = {x1, x1}, xs2 = {x2, x2};
    short8 af[4];
#pragma unroll
    for (int kb = 0; kb < 4; ++kb) {
      const int c0 = kb * 32 + lq * 8;
      unsigned u[4];
#pragma unroll
      for (int e2 = 0; e2 < 4; ++e2) {
        const int c = c0 + e2 * 2;
        f32x2 wx = *(const f32x2*)(sW1x + c);
        f32x2 wy = *(const f32x2*)(sW1y + c);
        f32x2 wz = *(const f32x2*)(sW1z + c);
        f32x2 wb = *(const f32x2*)(sW1b + c);
        f32x2 z  = pkfma(xs0, wx, pkfma(xs1, wy, pkfma(xs2, wz, wb)));
        u[e2] = cvtpk(celu01(z.x), celu01(z.y));
      }
      af[kb] = pack4(u[0], u[1], u[2], u[3]);
    }
    // each wave handles one output block ob = wave (disjoint cols, no atomics)
    {
      const int ob = wave;
      const int col = ob * 16 + lr;
      const float bv = sB2v[col];
      const short8* fb = sBfv + (ob * 4) * 64 + lane;
      f32x4 a = {bv, bv, bv, bv};
#pragma unroll
      for (int kb = 0; kb < 4; ++kb)
        a = __builtin_amdgcn_mfma_f32_16x16x32_bf16(af[kb], fb[kb * 64], a, 0, 0, 0);
#pragma unroll
      for (int j = 0; j < 4; ++j) {
        const int g = lq * 4 + j;
        if (g < G_) {
          float m = (float)((mbi >> g) & 1u);
          sAtm[g * 128 + col] += celu01(a[j]) * m;
        }
      }
    }
    if (wave == 0 && t < G_) sIm[t] = (float)((mbi >> t) & 1u);
    __syncthreads();   // sAtm final; sBf reads done (head reuses that space)
  }

  // ---------------- head MLP: 128 -> 64 -> 32 -> 16 -> 1 ----------------
  {
    const int g = t >> 4, u = t & 15;
    const bool act = (g < G_);        // t < 128
    if (act) {
      const f32x4* atm4 = (const f32x4*)(sAtm + g * 128);
#pragma unroll
      for (int rep = 0; rep < 4; ++rep) {
        const int o = rep * 16 + u;
        const f32x4* w4 = (const f32x4*)(p.HW[0] + o * 128);
        float z = p.Hb[0][o];
#pragma unroll 8
        for (int c = 0; c < 32; ++c) {
          f32x4 a = atm4[c], w = w4[c];
          z = fmaf(a.x, w.x, fmaf(a.y, w.y, fmaf(a.z, w.z, fmaf(a.w, w.w, z))));
        }
        sH1[g * 64 + o] = celu01(z);
      }
    }
    __syncthreads();
    if (act) {
      const f32x4* h14 = (const f32x4*)(sH1 + g * 64);
#pragma unroll
      for (int rep = 0; rep < 2; ++rep) {
        const int o = rep * 16 + u;
        const f32x4* w4 = (const f32x4*)(p.HW[1] + o * 64);
        float z = p.Hb[1][o];
#pragma unroll
        for (int c = 0; c < 16; ++c) {
          f32x4 a = h14[c], w = w4[c];
          z = fmaf(a.x, w.x, fmaf(a.y, w.y, fmaf(a.z, w.z, fmaf(a.w, w.w, z))));
        }
        sH2[g * 32 + o] = celu01(z);
      }
    }
    __syncthreads();
    if (act) {
      const f32x4* h24 = (const f32x4*)(sH2 + g * 32);
      const f32x4* w4 = (const f32x4*)(p.HW[2] + u * 32);
      float z = p.Hb[2][u];
#pragma unroll
      for (int c = 0; c < 8; ++c) {
        f32x4 a = h24[c], w = w4[c];
        z = fmaf(a.x, w.x, fmaf(a.y, w.y, fmaf(a.z, w.z, fmaf(a.w, w.w, z))));
      }
      sH3[g * 16 + u] = celu01(z);
    }
    __syncthreads();
    if (act && u == 0) {
      const f32x4* h34 = (const f32x4*)(sH3 + g * 16);
      const f32x4* w4 = (const f32x4*)p.HW[3];
      float z = p.Hb[3][0];
#pragma unroll
      for (int c = 0; c < 4; ++c) {
        f32x4 a = h34[c], w = w4[c];
        z = fmaf(a.x, w.x, fmaf(a.y, w.y, fmaf(a.z, w.z, fmaf(a.w, w.w, z))));
      }
      p.out[atom0 + g] = z * sIm[g];
    }
  }
}

extern "C" void kernel_launch(void* const* d_in, const int* in_sizes, int n_in,
                              void* d_out, int out_size, void* d_ws, size_t ws_size,
                              hipStream_t stream) {
  (void)in_sizes; (void)n_in; (void)out_size; (void)d_ws; (void)ws_size;
  DartParams p;
  // dict order: ai aj ak al | Wi1 bi1 Wi2 bi2 | Wj1 bj1 Wj2 bj2 | Wk1 bk1 Wk2 bk2
  //             | Wl1 bl1 Wl2 bl2 | W1 b1 W2 b2 W3 b3 W4 b4
  p.x[0] = (const float*)d_in[1];   // aj
  p.x[1] = (const float*)d_in[2];   // ak
  p.x[2] = (const float*)d_in[3];   // al
  p.x[3] = (const float*)d_in[0];   // ai
  p.W1[0] = (const float*)d_in[8];  p.b1[0] = (const float*)d_in[9];
  p.W2[0] = (const float*)d_in[10]; p.b2[0] = (const float*)d_in[11];
  p.W1[1] = (const float*)d_in[12]; p.b1[1] = (const float*)d_in[13];
  p.W2[1] = (const float*)d_in[14]; p.b2[1] = (const float*)d_in[15];
  p.W1[2] = (const float*)d_in[16]; p.b1[2] = (const float*)d_in[17];
  p.W2[2] = (const float*)d_in[18]; p.b2[2] = (const float*)d_in[19];
  p.W1[3] = (const float*)d_in[4];  p.b1[3] = (const float*)d_in[5];
  p.W2[3] = (const float*)d_in[6];  p.b2[3] = (const float*)d_in[7];
  p.HW[0] = (const float*)d_in[20]; p.Hb[0] = (const float*)d_in[21];
  p.HW[1] = (const float*)d_in[22]; p.Hb[1] = (const float*)d_in[23];
  p.HW[2] = (const float*)d_in[24]; p.Hb[2] = (const float*)d_in[25];
  p.HW[3] = (const float*)d_in[26]; p.Hb[3] = (const float*)d_in[27];
  p.out = (float*)d_out;

  dart_fused<<<dim3(NATOMS / G_), dim3(512), 0, stream>>>(p);
}

// Round 7
// 209.830 us; speedup vs baseline: 1.2597x; 1.2597x over previous
//
#include <hip/hip_runtime.h>

// DART_Net fused kernel, MI355X (gfx950). Round 7.
// B=64, N=128, M=64, LH=LO=128. Output [B*N] fp32.
//
// R7 vs R6/R5: R6 refuted pk_fma (VALU busy-time identical 126us) and
// 512-thread blocks (1 block/CU resident -> worse). Revert to R5 structure.
// Single change vs R5: B-frags for obs 6-7 move from LDS to per-wave
// REGISTERS (each wave global-loads its copy per species; W2 is L2-resident).
// LDS/block 39.9 KB -> 30.8 KB so 3-4 blocks co-reside (residency was
// empirically stuck at 2 blocks at ~40 KB despite nominal 160 KB/CU).
// VGPR budget: rfr 32 + af 32 + acc/frag/masks/misc ~= 115-122 < 128 cap.

typedef __attribute__((ext_vector_type(8))) short short8;   // bf16x8 frag
typedef __attribute__((ext_vector_type(4))) float f32x4;
typedef __attribute__((ext_vector_type(4))) unsigned uint4v;

#define G_ 8
#define NATOMS (64 * 128)

// LDS layout (bytes):
//   [    0, 24576)  sBf  : bf16 B-frags [ob*4+kb][lane], obs 0..5 only
//                   (after species: sH1 @0 [8*64], sH2 @2048, sH3 @3072)
//   [24576, 26880)  sW1  : f32x4[144] {w0,w1,w2,b1}, padded idx = c + (c>>3)
//   [26880, 27392)  sB2  : float[128]
//   [27392, 31488)  sAtm : float[8][128]
//   [31488, 31520)  sIm  : float[8]
#define LDS_BYTES 31520

struct DartParams {
  const float* x[4];    // aj, ak, al, ai
  const float* W1[4];
  const float* b1[4];
  const float* W2[4];
  const float* b2[4];
  const float* HW[4];   // 64x128, 32x64, 16x32, 1x16
  const float* Hb[4];
  float* out;
};

__device__ __forceinline__ float celu01(float z) {
  // celu(z, alpha=0.1) = max(z,0) + min(0.1*(exp(10z)-1), 0)
  float e = __builtin_amdgcn_exp2f(z * 14.42695040888963f);
  return fmaxf(z, 0.0f) + fminf(fmaf(0.1f, e, -0.1f), 0.0f);
}

__device__ __forceinline__ unsigned cvtpk(float a, float b) {
  unsigned r;
  asm("v_cvt_pk_bf16_f32 %0, %1, %2" : "=v"(r) : "v"(a), "v"(b));
  return r;
}
__device__ __forceinline__ short8 pack4(unsigned a, unsigned b, unsigned c, unsigned d) {
  uint4v u = {a, b, c, d};
  return __builtin_bit_cast(short8, u);
}

// Stage one species' weights: sW1/sB2 + LDS B-frags for obs 0-5; obs 6-7
// B-frags go to per-wave registers (rfr). Leading barrier protects prior
// readers, trailing barrier publishes.
__device__ __forceinline__ void stage_species(
    const float* W1g, const float* b1g, const float* W2g, const float* b2g,
    f32x4* sW1v, float* sB2v, short8* sBfv, short8 (&rfr)[2][4],
    int t, int lane, int lq, int lr, int wave) {
  __syncthreads();
  if (t < 128) {
    const float* w = W1g + t * 3;
    f32x4 v;
    v.x = w[0]; v.y = w[1]; v.z = w[2]; v.w = b1g[t];
    sW1v[t + (t >> 3)] = v;
    sB2v[t] = b2g[t];
  }
#pragma unroll
  for (int ff = 0; ff < 6; ++ff) {
    const int f  = wave * 6 + ff;            // 4 waves x 6 = 24 frags (obs 0-5)
    const int ob = f >> 2, kb = f & 3;
    const f32x4* src = (const f32x4*)(W2g + (ob * 16 + lr) * 128 + kb * 32 + lq * 8);
    f32x4 lo = src[0], hi = src[1];
    sBfv[f * 64 + lane] = pack4(cvtpk(lo.x, lo.y), cvtpk(lo.z, lo.w),
                                cvtpk(hi.x, hi.y), cvtpk(hi.z, hi.w));
  }
#pragma unroll
  for (int oo = 0; oo < 2; ++oo) {
    const int ob = 6 + oo;
#pragma unroll
    for (int kb = 0; kb < 4; ++kb) {
      const f32x4* src = (const f32x4*)(W2g + (ob * 16 + lr) * 128 + kb * 32 + lq * 8);
      f32x4 lo = src[0], hi = src[1];
      rfr[oo][kb] = pack4(cvtpk(lo.x, lo.y), cvtpk(lo.z, lo.w),
                          cvtpk(hi.x, hi.y), cvtpk(hi.z, hi.w));
    }
  }
  __syncthreads();
}

extern "C" __global__ __launch_bounds__(256, 2)
void dart_fused(DartParams p) {
  __shared__ __align__(16) char lds[LDS_BYTES];
  short8* sBfv = (short8*)lds;
  f32x4*  sW1v = (f32x4*)(lds + 24576);
  float*  sB2v = (float*)(lds + 26880);
  float*  sAtm = (float*)(lds + 27392);   // [8*128]
  float*  sIm  = (float*)(lds + 31488);   // [8]
  float*  sH1  = (float*)lds;             // [8*64]  (after species)
  float*  sH2  = (float*)(lds + 2048);    // [8*32]
  float*  sH3  = (float*)(lds + 3072);    // [8*16]

  const int t    = threadIdx.x;
  const int lane = t & 63;
  const int wave = t >> 6;        // 0..3 -> row block wave*16
  const int lq   = lane >> 4;
  const int lr   = lane & 15;
  const int atom0 = (int)blockIdx.x * G_;

  for (int i = t; i < G_ * 128; i += 256) sAtm[i] = 0.0f;

  short8 rfr[2][4];   // obs 6-7 B-frags, per-wave registers

  // ---------------- species j, k, l ----------------
#pragma unroll 1
  for (int s = 0; s < 3; ++s) {
    stage_species(p.W1[s], p.b1[s], p.W2[s], p.b2[s],
                  sW1v, sB2v, sBfv, rfr, t, lane, lq, lr, wave);

    float b2r[8];
#pragma unroll
    for (int ob = 0; ob < 8; ++ob) b2r[ob] = sB2v[ob * 16 + lr];

    const float* X = p.x[s];
    const int rowoff = wave * 16 + lr;

    // prefetch pair 0
    float pxa[3], pxb[3];
    {
      const float* xa = X + ((atom0 + 0) * 64 + rowoff) * 3;
      const float* xb = X + ((atom0 + 1) * 64 + rowoff) * 3;
      pxa[0] = xa[0]; pxa[1] = xa[1]; pxa[2] = xa[2];
      pxb[0] = xb[0]; pxb[1] = xb[1]; pxb[2] = xb[2];
    }

#pragma unroll 1
    for (int pp = 0; pp < G_ / 2; ++pp) {
      const int g0 = 2 * pp, g1 = 2 * pp + 1;
      const float xa0 = pxa[0], xa1 = pxa[1], xa2 = pxa[2];
      const float xb0 = pxb[0], xb1 = pxb[1], xb2 = pxb[2];
      if (pp + 1 < G_ / 2) {
        const float* xa = X + ((atom0 + g0 + 2) * 64 + rowoff) * 3;
        const float* xb = X + ((atom0 + g1 + 2) * 64 + rowoff) * 3;
        pxa[0] = xa[0]; pxa[1] = xa[1]; pxa[2] = xa[2];
        pxb[0] = xb[0]; pxb[1] = xb[1]; pxb[2] = xb[2];
      }
      const unsigned mwa = (unsigned)__ballot((xa0 + xa1 + xa2) != 0.0f);
      const unsigned mwb = (unsigned)__ballot((xb0 + xb1 + xb2) != 0.0f);
      float mra[4], mrb[4];
#pragma unroll
      for (int j = 0; j < 4; ++j) {
        mra[j] = (float)((mwa >> (lq * 4 + j)) & 1u);
        mrb[j] = (float)((mwb >> (lq * 4 + j)) & 1u);
      }

      // ---- layer 1 + celu + cvt_pk pack, A-frag layout, both atoms ----
      short8 afa[4], afb[4];
#pragma unroll
      for (int kb = 0; kb < 4; ++kb) {
        const f32x4* wrow = sW1v + kb * 36 + lq * 9;   // padded index
        unsigned ua[4], ub[4];
#pragma unroll
        for (int e2 = 0; e2 < 4; ++e2) {
          f32x4 wA = wrow[2 * e2], wB = wrow[2 * e2 + 1];
          float aA = celu01(fmaf(xa0, wA.x, fmaf(xa1, wA.y, fmaf(xa2, wA.z, wA.w))));
          float aB = celu01(fmaf(xa0, wB.x, fmaf(xa1, wB.y, fmaf(xa2, wB.z, wB.w))));
          ua[e2] = cvtpk(aA, aB);
          float bA = celu01(fmaf(xb0, wA.x, fmaf(xb1, wA.y, fmaf(xb2, wA.z, wA.w))));
          float bB = celu01(fmaf(xb0, wB.x, fmaf(xb1, wB.y, fmaf(xb2, wB.z, wB.w))));
          ub[e2] = cvtpk(bA, bB);
        }
        afa[kb] = pack4(ua[0], ua[1], ua[2], ua[3]);
        afb[kb] = pack4(ub[0], ub[1], ub[2], ub[3]);
      }

      // ---- per-ob: B-frags (LDS obs 0-5, regs obs 6-7), 8 MFMAs, epilogue ----
#pragma unroll
      for (int ob = 0; ob < 8; ++ob) {
        const float bv = b2r[ob];
        f32x4 a0 = {bv, bv, bv, bv};
        f32x4 a1 = a0;
        if (ob < 6) {
          const short8* fb = sBfv + (ob * 4) * 64 + lane;
#pragma unroll
          for (int kb = 0; kb < 4; ++kb) {
            short8 fr = fb[kb * 64];
            a0 = __builtin_amdgcn_mfma_f32_16x16x32_bf16(afa[kb], fr, a0, 0, 0, 0);
            a1 = __builtin_amdgcn_mfma_f32_16x16x32_bf16(afb[kb], fr, a1, 0, 0, 0);
          }
        } else {
#pragma unroll
          for (int kb = 0; kb < 4; ++kb) {
            short8 fr = rfr[ob - 6][kb];
            a0 = __builtin_amdgcn_mfma_f32_16x16x32_bf16(afa[kb], fr, a0, 0, 0, 0);
            a1 = __builtin_amdgcn_mfma_f32_16x16x32_bf16(afb[kb], fr, a1, 0, 0, 0);
          }
        }
        float p0 = 0.0f, p1 = 0.0f;
#pragma unroll
        for (int j = 0; j < 4; ++j) {
          p0 = fmaf(celu01(a0[j]), mra[j], p0);
          p1 = fmaf(celu01(a1[j]), mrb[j], p1);
        }
        p0 += __shfl_xor(p0, 16, 64);
        p0 += __shfl_xor(p0, 32, 64);
        p1 += __shfl_xor(p1, 16, 64);
        p1 += __shfl_xor(p1, 32, 64);
        const int col = ob * 16 + lr;
        if (lane < 16) {
          atomicAdd(&sAtm[g0 * 128 + col], p0);
          atomicAdd(&sAtm[g1 * 128 + col], p1);
        }
      }
    }
  }

  // ---------------- species i: one 16-row GEMM (rows = atoms) ----------------
  {
    stage_species(p.W1[3], p.b1[3], p.W2[3], p.b2[3],
                  sW1v, sB2v, sBfv, rfr, t, lane, lq, lr, wave);
    // (leading barrier also guarantees all j/k/l sAtm atomics complete)

    const int ri = min(atom0 + lr, NATOMS - 1);
    const float* xp = p.x[3] + ri * 3;
    const float x0 = xp[0], x1 = xp[1], x2 = xp[2];
    const unsigned mbi = (unsigned)__ballot((x0 + x1 + x2) != 0.0f);

    short8 af[4];
#pragma unroll
    for (int kb = 0; kb < 4; ++kb) {
      const f32x4* wrow = sW1v + kb * 36 + lq * 9;
      unsigned u[4];
#pragma unroll
      for (int e2 = 0; e2 < 4; ++e2) {
        f32x4 wA = wrow[2 * e2], wB = wrow[2 * e2 + 1];
        float cA = celu01(fmaf(x0, wA.x, fmaf(x1, wA.y, fmaf(x2, wA.z, wA.w))));
        float cB = celu01(fmaf(x0, wB.x, fmaf(x1, wB.y, fmaf(x2, wB.z, wB.w))));
        u[e2] = cvtpk(cA, cB);
      }
      af[kb] = pack4(u[0], u[1], u[2], u[3]);
    }
    // each wave handles 2 output blocks: ob = wave*2, wave*2+1 (disjoint cols)
#pragma unroll
    for (int oo = 0; oo < 2; ++oo) {
      const int ob = wave * 2 + oo;
      const int col = ob * 16 + lr;
      const float bv = sB2v[col];
      f32x4 a = {bv, bv, bv, bv};
      if (wave == 3) {
#pragma unroll
        for (int kb = 0; kb < 4; ++kb)
          a = __builtin_amdgcn_mfma_f32_16x16x32_bf16(af[kb], rfr[oo][kb], a, 0, 0, 0);
      } else {
        const short8* fb = sBfv + (ob * 4) * 64 + lane;
#pragma unroll
        for (int kb = 0; kb < 4; ++kb)
          a = __builtin_amdgcn_mfma_f32_16x16x32_bf16(af[kb], fb[kb * 64], a, 0, 0, 0);
      }
#pragma unroll
      for (int j = 0; j < 4; ++j) {
        const int g = lq * 4 + j;
        if (g < G_) {
          float m = (float)((mbi >> g) & 1u);
          sAtm[g * 128 + col] += celu01(a[j]) * m;
        }
      }
    }
    if (wave == 0 && t < G_) sIm[t] = (float)((mbi >> t) & 1u);
    __syncthreads();   // sAtm final; sBf reads done (head reuses that space)
  }

  // ---------------- head MLP: 128 -> 64 -> 32 -> 16 -> 1 ----------------
  {
    const int g = t >> 4, u = t & 15;
    const bool act = (g < G_);
    if (act) {
      const f32x4* atm4 = (const f32x4*)(sAtm + g * 128);
#pragma unroll
      for (int rep = 0; rep < 4; ++rep) {
        const int o = rep * 16 + u;
        const f32x4* w4 = (const f32x4*)(p.HW[0] + o * 128);
        float z = p.Hb[0][o];
#pragma unroll 8
        for (int c = 0; c < 32; ++c) {
          f32x4 a = atm4[c], w = w4[c];
          z = fmaf(a.x, w.x, fmaf(a.y, w.y, fmaf(a.z, w.z, fmaf(a.w, w.w, z))));
        }
        sH1[g * 64 + o] = celu01(z);
      }
    }
    __syncthreads();
    if (act) {
      const f32x4* h14 = (const f32x4*)(sH1 + g * 64);
#pragma unroll
      for (int rep = 0; rep < 2; ++rep) {
        const int o = rep * 16 + u;
        const f32x4* w4 = (const f32x4*)(p.HW[1] + o * 64);
        float z = p.Hb[1][o];
#pragma unroll
        for (int c = 0; c < 16; ++c) {
          f32x4 a = h14[c], w = w4[c];
          z = fmaf(a.x, w.x, fmaf(a.y, w.y, fmaf(a.z, w.z, fmaf(a.w, w.w, z))));
        }
        sH2[g * 32 + o] = celu01(z);
      }
    }
    __syncthreads();
    if (act) {
      const f32x4* h24 = (const f32x4*)(sH2 + g * 32);
      const f32x4* w4 = (const f32x4*)(p.HW[2] + u * 32);
      float z = p.Hb[2][u];
#pragma unroll
      for (int c = 0; c < 8; ++c) {
        f32x4 a = h24[c], w = w4[c];
        z = fmaf(a.x, w.x, fmaf(a.y, w.y, fmaf(a.z, w.z, fmaf(a.w, w.w, z))));
      }
      sH3[g * 16 + u] = celu01(z);
    }
    __syncthreads();
    if (act && u == 0) {
      const f32x4* h34 = (const f32x4*)(sH3 + g * 16);
      const f32x4* w4 = (const f32x4*)p.HW[3];
      float z = p.Hb[3][0];
#pragma unroll
      for (int c = 0; c < 4; ++c) {
        f32x4 a = h34[c], w = w4[c];
        z = fmaf(a.x, w.x, fmaf(a.y, w.y, fmaf(a.z, w.z, fmaf(a.w, w.w, z))));
      }
      p.out[atom0 + g] = z * sIm[g];
    }
  }
}

extern "C" void kernel_launch(void* const* d_in, const int* in_sizes, int n_in,
                              void* d_out, int out_size, void* d_ws, size_t ws_size,
                              hipStream_t stream) {
  (void)in_sizes; (void)n_in; (void)out_size; (void)d_ws; (void)ws_size;
  DartParams p;
  // dict order: ai aj ak al | Wi1 bi1 Wi2 bi2 | Wj1 bj1 Wj2 bj2 | Wk1 bk1 Wk2 bk2
  //             | Wl1 bl1 Wl2 bl2 | W1 b1 W2 b2 W3 b3 W4 b4
  p.x[0] = (const float*)d_in[1];   // aj
  p.x[1] = (const float*)d_in[2];   // ak
  p.x[2] = (const float*)d_in[3];   // al
  p.x[3] = (const float*)d_in[0];   // ai
  p.W1[0] = (const float*)d_in[8];  p.b1[0] = (const float*)d_in[9];
  p.W2[0] = (const float*)d_in[10]; p.b2[0] = (const float*)d_in[11];
  p.W1[1] = (const float*)d_in[12]; p.b1[1] = (const float*)d_in[13];
  p.W2[1] = (const float*)d_in[14]; p.b2[1] = (const float*)d_in[15];
  p.W1[2] = (const float*)d_in[16]; p.b1[2] = (const float*)d_in[17];
  p.W2[2] = (const float*)d_in[18]; p.b2[2] = (const float*)d_in[19];
  p.W1[3] = (const float*)d_in[4];  p.b1[3] = (const float*)d_in[5];
  p.W2[3] = (const float*)d_in[6];  p.b2[3] = (const float*)d_in[7];
  p.HW[0] = (const float*)d_in[20]; p.Hb[0] = (const float*)d_in[21];
  p.HW[1] = (const float*)d_in[22]; p.Hb[1] = (const float*)d_in[23];
  p.HW[2] = (const float*)d_in[24]; p.Hb[2] = (const float*)d_in[25];
  p.HW[3] = (const float*)d_in[26]; p.Hb[3] = (const float*)d_in[27];
  p.out = (float*)d_out;

  dart_fused<<<dim3(NATOMS / G_), dim3(256), 0, stream>>>(p);
}

// Round 8
// 172.894 us; speedup vs baseline: 1.5288x; 1.2136x over previous
//
#include <hip/hip_runtime.h>

// DART_Net fused kernel, MI355X (gfx950). Round 8.
// B=64, N=128, M=64, LH=LO=128. Output [B*N] fp32.
//
// R8 = R5 (185us champion) with ONE change: __launch_bounds__(256, 4).
// Theory: every round R1-R7 measured occupancy pinned at ~25% = exactly the
// declared min-waves/EU of 2, across VGPR 68..128 and LDS 26..40 KB -- the
// launch-bounds metadata, not any HW pool, is limiting residency. Declaring
// 4 waves/EU caps VGPR at 128 (R5 uses 84 -> codegen unchanged, no spill)
// and should allow 4 blocks/CU (LDS 39.9KB x 4 = 159.7 <= 160 KiB exactly).

typedef __attribute__((ext_vector_type(8))) short short8;   // bf16x8 frag
typedef __attribute__((ext_vector_type(4))) float f32x4;
typedef __attribute__((ext_vector_type(4))) unsigned uint4v;

#define G_ 8
#define NATOMS (64 * 128)

// LDS layout (bytes):
//   [    0, 32768)  sBf  : bf16 B-frags [ob*4+kb][lane] (16B each)
//                   (after species: sH1 @0 [8*64], sH2 @2048, sH3 @3072)
//   [32768, 35072)  sW1  : f32x4[144] {w0,w1,w2,b1}, padded idx = c + (c>>3)
//   [35072, 35584)  sB2  : float[128]
//   [35584, 39680)  sAtm : float[8][128]
//   [39680, 39712)  sIm  : float[8]
#define LDS_BYTES 39712

struct DartParams {
  const float* x[4];    // aj, ak, al, ai
  const float* W1[4];
  const float* b1[4];
  const float* W2[4];
  const float* b2[4];
  const float* HW[4];   // 64x128, 32x64, 16x32, 1x16
  const float* Hb[4];
  float* out;
};

__device__ __forceinline__ float celu01(float z) {
  // celu(z, alpha=0.1) = max(z,0) + min(0.1*(exp(10z)-1), 0)
  float e = __builtin_amdgcn_exp2f(z * 14.42695040888963f);
  return fmaxf(z, 0.0f) + fminf(fmaf(0.1f, e, -0.1f), 0.0f);
}

__device__ __forceinline__ unsigned cvtpk(float a, float b) {
  unsigned r;
  asm("v_cvt_pk_bf16_f32 %0, %1, %2" : "=v"(r) : "v"(a), "v"(b));
  return r;
}
__device__ __forceinline__ short8 pack4(unsigned a, unsigned b, unsigned c, unsigned d) {
  uint4v u = {a, b, c, d};
  return __builtin_bit_cast(short8, u);
}

// Stage one species' weights into LDS: sW1 (padded f32x4), sB2, and bf16 W2
// B-fragments [ob*4+kb][lane]. Leading barrier protects prior readers,
// trailing barrier publishes.
__device__ __forceinline__ void stage_species(
    const float* W1g, const float* b1g, const float* W2g, const float* b2g,
    f32x4* sW1v, float* sB2v, short8* sBfv,
    int t, int lane, int lq, int lr, int wave) {
  __syncthreads();
  if (t < 128) {
    const float* w = W1g + t * 3;
    f32x4 v;
    v.x = w[0]; v.y = w[1]; v.z = w[2]; v.w = b1g[t];
    sW1v[t + (t >> 3)] = v;
    sB2v[t] = b2g[t];
  }
#pragma unroll
  for (int ff = 0; ff < 8; ++ff) {
    const int f  = wave * 8 + ff;
    const int ob = f >> 2, kb = f & 3;
    const f32x4* src = (const f32x4*)(W2g + (ob * 16 + lr) * 128 + kb * 32 + lq * 8);
    f32x4 lo = src[0], hi = src[1];
    sBfv[f * 64 + lane] = pack4(cvtpk(lo.x, lo.y), cvtpk(lo.z, lo.w),
                                cvtpk(hi.x, hi.y), cvtpk(hi.z, hi.w));
  }
  __syncthreads();
}

extern "C" __global__ __launch_bounds__(256, 4)
void dart_fused(DartParams p) {
  __shared__ __align__(16) char lds[LDS_BYTES];
  short8* sBfv = (short8*)lds;
  f32x4*  sW1v = (f32x4*)(lds + 32768);
  float*  sB2v = (float*)(lds + 35072);
  float*  sAtm = (float*)(lds + 35584);   // [8*128]
  float*  sIm  = (float*)(lds + 39680);   // [8]
  float*  sH1  = (float*)lds;             // [8*64]  (after species)
  float*  sH2  = (float*)(lds + 2048);    // [8*32]
  float*  sH3  = (float*)(lds + 3072);    // [8*16]

  const int t    = threadIdx.x;
  const int lane = t & 63;
  const int wave = t >> 6;        // 0..3 -> row block wave*16
  const int lq   = lane >> 4;
  const int lr   = lane & 15;
  const int atom0 = (int)blockIdx.x * G_;

  for (int i = t; i < G_ * 128; i += 256) sAtm[i] = 0.0f;

  // ---------------- species j, k, l ----------------
#pragma unroll 1
  for (int s = 0; s < 3; ++s) {
    stage_species(p.W1[s], p.b1[s], p.W2[s], p.b2[s],
                  sW1v, sB2v, sBfv, t, lane, lq, lr, wave);

    float b2r[8];
#pragma unroll
    for (int ob = 0; ob < 8; ++ob) b2r[ob] = sB2v[ob * 16 + lr];

    const float* X = p.x[s];
    const int rowoff = wave * 16 + lr;

    // prefetch pair 0
    float pxa[3], pxb[3];
    {
      const float* xa = X + ((atom0 + 0) * 64 + rowoff) * 3;
      const float* xb = X + ((atom0 + 1) * 64 + rowoff) * 3;
      pxa[0] = xa[0]; pxa[1] = xa[1]; pxa[2] = xa[2];
      pxb[0] = xb[0]; pxb[1] = xb[1]; pxb[2] = xb[2];
    }

#pragma unroll 1
    for (int pp = 0; pp < G_ / 2; ++pp) {
      const int g0 = 2 * pp, g1 = 2 * pp + 1;
      const float xa0 = pxa[0], xa1 = pxa[1], xa2 = pxa[2];
      const float xb0 = pxb[0], xb1 = pxb[1], xb2 = pxb[2];
      if (pp + 1 < G_ / 2) {
        const float* xa = X + ((atom0 + g0 + 2) * 64 + rowoff) * 3;
        const float* xb = X + ((atom0 + g1 + 2) * 64 + rowoff) * 3;
        pxa[0] = xa[0]; pxa[1] = xa[1]; pxa[2] = xa[2];
        pxb[0] = xb[0]; pxb[1] = xb[1]; pxb[2] = xb[2];
      }
      const unsigned mwa = (unsigned)__ballot((xa0 + xa1 + xa2) != 0.0f);
      const unsigned mwb = (unsigned)__ballot((xb0 + xb1 + xb2) != 0.0f);
      float mra[4], mrb[4];
#pragma unroll
      for (int j = 0; j < 4; ++j) {
        mra[j] = (float)((mwa >> (lq * 4 + j)) & 1u);
        mrb[j] = (float)((mwb >> (lq * 4 + j)) & 1u);
      }

      // ---- layer 1 + celu + cvt_pk pack, A-frag layout, both atoms ----
      short8 afa[4], afb[4];
#pragma unroll
      for (int kb = 0; kb < 4; ++kb) {
        const f32x4* wrow = sW1v + kb * 36 + lq * 9;   // padded index
        unsigned ua[4], ub[4];
#pragma unroll
        for (int e2 = 0; e2 < 4; ++e2) {
          f32x4 wA = wrow[2 * e2], wB = wrow[2 * e2 + 1];
          float aA = celu01(fmaf(xa0, wA.x, fmaf(xa1, wA.y, fmaf(xa2, wA.z, wA.w))));
          float aB = celu01(fmaf(xa0, wB.x, fmaf(xa1, wB.y, fmaf(xa2, wB.z, wB.w))));
          ua[e2] = cvtpk(aA, aB);
          float bA = celu01(fmaf(xb0, wA.x, fmaf(xb1, wA.y, fmaf(xb2, wA.z, wA.w))));
          float bB = celu01(fmaf(xb0, wB.x, fmaf(xb1, wB.y, fmaf(xb2, wB.z, wB.w))));
          ub[e2] = cvtpk(bA, bB);
        }
        afa[kb] = pack4(ua[0], ua[1], ua[2], ua[3]);
        afb[kb] = pack4(ub[0], ub[1], ub[2], ub[3]);
      }

      // ---- per-ob: shared B-frag reads, 8 MFMAs (2 atoms), epilogue ----
#pragma unroll
      for (int ob = 0; ob < 8; ++ob) {
        const short8* fb = sBfv + (ob * 4) * 64 + lane;
        const float bv = b2r[ob];
        f32x4 a0 = {bv, bv, bv, bv};
        f32x4 a1 = a0;
#pragma unroll
        for (int kb = 0; kb < 4; ++kb) {
          short8 fr = fb[kb * 64];
          a0 = __builtin_amdgcn_mfma_f32_16x16x32_bf16(afa[kb], fr, a0, 0, 0, 0);
          a1 = __builtin_amdgcn_mfma_f32_16x16x32_bf16(afb[kb], fr, a1, 0, 0, 0);
        }
        float p0 = 0.0f, p1 = 0.0f;
#pragma unroll
        for (int j = 0; j < 4; ++j) {
          p0 = fmaf(celu01(a0[j]), mra[j], p0);
          p1 = fmaf(celu01(a1[j]), mrb[j], p1);
        }
        p0 += __shfl_xor(p0, 16, 64);
        p0 += __shfl_xor(p0, 32, 64);
        p1 += __shfl_xor(p1, 16, 64);
        p1 += __shfl_xor(p1, 32, 64);
        const int col = ob * 16 + lr;
        if (lane < 16) {
          atomicAdd(&sAtm[g0 * 128 + col], p0);
          atomicAdd(&sAtm[g1 * 128 + col], p1);
        }
      }
    }
  }

  // ---------------- species i: one 16-row GEMM (rows = atoms) ----------------
  {
    stage_species(p.W1[3], p.b1[3], p.W2[3], p.b2[3],
                  sW1v, sB2v, sBfv, t, lane, lq, lr, wave);
    // (leading barrier also guarantees all j/k/l sAtm atomics complete)

    const int ri = min(atom0 + lr, NATOMS - 1);
    const float* xp = p.x[3] + ri * 3;
    const float x0 = xp[0], x1 = xp[1], x2 = xp[2];
    const unsigned mbi = (unsigned)__ballot((x0 + x1 + x2) != 0.0f);

    short8 af[4];
#pragma unroll
    for (int kb = 0; kb < 4; ++kb) {
      const f32x4* wrow = sW1v + kb * 36 + lq * 9;
      unsigned u[4];
#pragma unroll
      for (int e2 = 0; e2 < 4; ++e2) {
        f32x4 wA = wrow[2 * e2], wB = wrow[2 * e2 + 1];
        float cA = celu01(fmaf(x0, wA.x, fmaf(x1, wA.y, fmaf(x2, wA.z, wA.w))));
        float cB = celu01(fmaf(x0, wB.x, fmaf(x1, wB.y, fmaf(x2, wB.z, wB.w))));
        u[e2] = cvtpk(cA, cB);
      }
      af[kb] = pack4(u[0], u[1], u[2], u[3]);
    }
    // each wave handles 2 output blocks: ob = wave*2, wave*2+1 (disjoint cols)
#pragma unroll
    for (int oo = 0; oo < 2; ++oo) {
      const int ob = wave * 2 + oo;
      const int col = ob * 16 + lr;
      const float bv = sB2v[col];
      const short8* fb = sBfv + (ob * 4) * 64 + lane;
      f32x4 a = {bv, bv, bv, bv};
#pragma unroll
      for (int kb = 0; kb < 4; ++kb)
        a = __builtin_amdgcn_mfma_f32_16x16x32_bf16(af[kb], fb[kb * 64], a, 0, 0, 0);
#pragma unroll
      for (int j = 0; j < 4; ++j) {
        const int g = lq * 4 + j;
        if (g < G_) {
          float m = (float)((mbi >> g) & 1u);
          sAtm[g * 128 + col] += celu01(a[j]) * m;
        }
      }
    }
    if (wave == 0 && t < G_) sIm[t] = (float)((mbi >> t) & 1u);
    __syncthreads();   // sAtm final; sBf reads done (head reuses that space)
  }

  // ---------------- head MLP: 128 -> 64 -> 32 -> 16 -> 1 ----------------
  {
    const int g = t >> 4, u = t & 15;
    const bool act = (g < G_);
    if (act) {
      const f32x4* atm4 = (const f32x4*)(sAtm + g * 128);
#pragma unroll
      for (int rep = 0; rep < 4; ++rep) {
        const int o = rep * 16 + u;
        const f32x4* w4 = (const f32x4*)(p.HW[0] + o * 128);
        float z = p.Hb[0][o];
#pragma unroll 8
        for (int c = 0; c < 32; ++c) {
          f32x4 a = atm4[c], w = w4[c];
          z = fmaf(a.x, w.x, fmaf(a.y, w.y, fmaf(a.z, w.z, fmaf(a.w, w.w, z))));
        }
        sH1[g * 64 + o] = celu01(z);
      }
    }
    __syncthreads();
    if (act) {
      const f32x4* h14 = (const f32x4*)(sH1 + g * 64);
#pragma unroll
      for (int rep = 0; rep < 2; ++rep) {
        const int o = rep * 16 + u;
        const f32x4* w4 = (const f32x4*)(p.HW[1] + o * 64);
        float z = p.Hb[1][o];
#pragma unroll
        for (int c = 0; c < 16; ++c) {
          f32x4 a = h14[c], w = w4[c];
          z = fmaf(a.x, w.x, fmaf(a.y, w.y, fmaf(a.z, w.z, fmaf(a.w, w.w, z))));
        }
        sH2[g * 32 + o] = celu01(z);
      }
    }
    __syncthreads();
    if (act) {
      const f32x4* h24 = (const f32x4*)(sH2 + g * 32);
      const f32x4* w4 = (const f32x4*)(p.HW[2] + u * 32);
      float z = p.Hb[2][u];
#pragma unroll
      for (int c = 0; c < 8; ++c) {
        f32x4 a = h24[c], w = w4[c];
        z = fmaf(a.x, w.x, fmaf(a.y, w.y, fmaf(a.z, w.z, fmaf(a.w, w.w, z))));
      }
      sH3[g * 16 + u] = celu01(z);
    }
    __syncthreads();
    if (act && u == 0) {
      const f32x4* h34 = (const f32x4*)(sH3 + g * 16);
      const f32x4* w4 = (const f32x4*)p.HW[3];
      float z = p.Hb[3][0];
#pragma unroll
      for (int c = 0; c < 4; ++c) {
        f32x4 a = h34[c], w = w4[c];
        z = fmaf(a.x, w.x, fmaf(a.y, w.y, fmaf(a.z, w.z, fmaf(a.w, w.w, z))));
      }
      p.out[atom0 + g] = z * sIm[g];
    }
  }
}

extern "C" void kernel_launch(void* const* d_in, const int* in_sizes, int n_in,
                              void* d_out, int out_size, void* d_ws, size_t ws_size,
                              hipStream_t stream) {
  (void)in_sizes; (void)n_in; (void)out_size; (void)d_ws; (void)ws_size;
  DartParams p;
  // dict order: ai aj ak al | Wi1 bi1 Wi2 bi2 | Wj1 bj1 Wj2 bj2 | Wk1 bk1 Wk2 bk2
  //             | Wl1 bl1 Wl2 bl2 | W1 b1 W2 b2 W3 b3 W4 b4
  p.x[0] = (const float*)d_in[1];   // aj
  p.x[1] = (const float*)d_in[2];   // ak
  p.x[2] = (const float*)d_in[3];   // al
  p.x[3] = (const float*)d_in[0];   // ai
  p.W1[0] = (const float*)d_in[8];  p.b1[0] = (const float*)d_in[9];
  p.W2[0] = (const float*)d_in[10]; p.b2[0] = (const float*)d_in[11];
  p.W1[1] = (const float*)d_in[12]; p.b1[1] = (const float*)d_in[13];
  p.W2[1] = (const float*)d_in[14]; p.b2[1] = (const float*)d_in[15];
  p.W1[2] = (const float*)d_in[16]; p.b1[2] = (const float*)d_in[17];
  p.W2[2] = (const float*)d_in[18]; p.b2[2] = (const float*)d_in[19];
  p.W1[3] = (const float*)d_in[4];  p.b1[3] = (const float*)d_in[5];
  p.W2[3] = (const float*)d_in[6];  p.b2[3] = (const float*)d_in[7];
  p.HW[0] = (const float*)d_in[20]; p.Hb[0] = (const float*)d_in[21];
  p.HW[1] = (const float*)d_in[22]; p.Hb[1] = (const float*)d_in[23];
  p.HW[2] = (const float*)d_in[24]; p.Hb[2] = (const float*)d_in[25];
  p.HW[3] = (const float*)d_in[26]; p.Hb[3] = (const float*)d_in[27];
  p.out = (float*)d_out;

  dart_fused<<<dim3(NATOMS / G_), dim3(256), 0, stream>>>(p);
}